// Round 6
// baseline (772.404 us; speedup 1.0000x reference)
//
#include <hip/hip_runtime.h>
#include <stdint.h>

#define M_DIM 16384
#define N_DIM 4096
#define K_DIM 4096

#define BM 256
#define BN 128
#define BK 128
#define NT (K_DIM / BK)  // 32 K-tiles

typedef int i32x4 __attribute__((ext_vector_type(4)));

// ---- async global->LDS 16B (dest = wave-uniform base, HW adds lane*16) ----
__device__ __forceinline__ void async16(const uint8_t* g, uint8_t* l) {
    __builtin_amdgcn_global_load_lds(
        (const __attribute__((address_space(1))) void*)g,
        (__attribute__((address_space(3))) void*)l,
        16, 0, 0);
}

// ---------------- weight pack: int32 -> int8 ----------------
__global__ __launch_bounds__(256) void pack_w_kernel(const int* __restrict__ w32,
                                                     uint32_t* __restrict__ w8,
                                                     int n4) {
    int i = blockIdx.x * 256 + threadIdx.x;
    if (i < n4) {
        const int4 v = reinterpret_cast<const int4*>(w32)[i];
        uint32_t p = (uint32_t)(v.x & 255) | ((uint32_t)(v.y & 255) << 8) |
                     ((uint32_t)(v.z & 255) << 16) | ((uint32_t)(v.w & 255) << 24);
        w8[i] = p;
    }
}

// ---------------- per-row dynamic activation quant ----------------
__global__ __launch_bounds__(256) void quant_kernel(const float* __restrict__ x,
                                                    uint32_t* __restrict__ xq,
                                                    float* __restrict__ xscale) {
    const int m = blockIdx.x;
    const int t = threadIdx.x;
    const float4* row = reinterpret_cast<const float4*>(x + (size_t)m * K_DIM);
    float4 v[4];
    float amax = 0.0f;
#pragma unroll
    for (int i = 0; i < 4; ++i) {
        v[i] = row[t + i * 256];
        amax = fmaxf(amax, fmaxf(fmaxf(fabsf(v[i].x), fabsf(v[i].y)),
                                 fmaxf(fabsf(v[i].z), fabsf(v[i].w))));
    }
#pragma unroll
    for (int off = 32; off > 0; off >>= 1) amax = fmaxf(amax, __shfl_xor(amax, off));
    __shared__ float smax[4];
    if ((t & 63) == 0) smax[t >> 6] = amax;
    __syncthreads();
    amax = fmaxf(fmaxf(smax[0], smax[1]), fmaxf(smax[2], smax[3]));
    const float scale = amax / 127.0f;
    const float s = fmaxf(scale, 1e-8f);
    if (t == 0) xscale[m] = scale;
    uint32_t* orow = xq + (size_t)m * (K_DIM / 4);
#pragma unroll
    for (int i = 0; i < 4; ++i) {
        int q0 = __float2int_rn(v[i].x / s);
        int q1 = __float2int_rn(v[i].y / s);
        int q2 = __float2int_rn(v[i].z / s);
        int q3 = __float2int_rn(v[i].w / s);
        q0 = max(-127, min(127, q0));
        q1 = max(-127, min(127, q1));
        q2 = max(-127, min(127, q2));
        q3 = max(-127, min(127, q3));
        uint32_t p = (uint32_t)(q0 & 255) | ((uint32_t)(q1 & 255) << 8) |
                     ((uint32_t)(q2 & 255) << 16) | ((uint32_t)(q3 & 255) << 24);
        orow[t + i * 256] = p;
    }
}

// ---------------- int8 GEMM, 256x128, 2 blocks/CU, counted-vmcnt ----------
// 256 threads = 4 waves (2M x 2N), per-wave output 128x64, 16x16x64 MFMA.
// LDS 80KB: A double-buffer (2x32KB) + B single-buffer (16KB) -> exactly
// 2 blocks/CU; cross-block desync covers each block's serial phases (m114).
// Steady state per tile t (curA = ldsA[t&1]):
//   entry: tile t data landed (boundary vmcnt+BAR); A(t+1) 8 loads in flight
//   read kk0 (12) | read kk1 (12)       ; kk1 drains under cluster0
//   lgkm(12); cluster0; lgkm(0)
//   MID BAR                             ; all waves done reading curA & B
//   stage B(t+1)->ldsB [4]              ; window ~= cluster1
//   stage A(t+2)->curA [8]              ; window ~= 1.5 tiles
//   cluster1
//   vmcnt(8)                            ; drains A(t+1)+B(t+1), leaves A(t+2)
//   BOUNDARY BAR
// Swizzle: LDS(row r, unit p) holds global unit p^(r&7) (pre-swizzled source,
// linear LDS dest, XOR on ds_read). Proven 0 bank conflicts (r1-r3).
__global__ __launch_bounds__(256, 2) void gemm_kernel(
    const uint8_t* __restrict__ Aq, const float* __restrict__ ascale,
    const uint8_t* __restrict__ Bq, const float* __restrict__ wscale,
    float* __restrict__ out) {
    __shared__ uint8_t lds[2 * BM * BK + BN * BK];  // 64KB + 16KB = 80KB
    uint8_t* ldsA0 = lds;
    uint8_t* ldsA1 = lds + BM * BK;
    uint8_t* ldsB = lds + 2 * BM * BK;

    const int tid = threadIdx.x;
    const int lane = tid & 63;
    const int w = tid >> 6;    // 0..3
    const int wr = w >> 1;     // 0..1 -> M offset wr*128
    const int wc = w & 1;      // 0..1 -> N offset wc*64
    const int lr = lane & 15;  // row within 16x16 fragment
    const int lg = lane >> 4;  // k-group 0..3 (16B each)

    // XCD-aware bijective swizzle (2048 blocks, 2048%8==0); same-XCD blocks
    // are nt-major (consecutive share A-rows -> A L2-resident per chunk)
    const int bid = blockIdx.x;
    const int swz = (bid & 7) * (2048 / 8) + (bid >> 3);
    const size_t row0 = (size_t)(swz >> 5) * BM;  // 64 M-tiles
    const size_t col0 = (size_t)(swz & 31) * BN;  // 32 N-tiles
    const uint8_t* Ab = Aq + row0 * K_DIM;
    const uint8_t* Bb = Bq + col0 * K_DIM;

    i32x4 acc[8][4];
#pragma unroll
    for (int i = 0; i < 8; ++i)
#pragma unroll
        for (int j = 0; j < 4; ++j) acc[i][j] = (i32x4){0, 0, 0, 0};

    // stage A tile (32KB = 2048x16B units): 8 iters, idx = it*256+tid
#define STAGE_A(DST, KT)                                                         \
    do {                                                                         \
        _Pragma("unroll") for (int it_ = 0; it_ < 8; ++it_) {                    \
            const int idx_ = it_ * 256 + tid;                                    \
            const int m_ = idx_ >> 3, p_ = idx_ & 7;                             \
            async16(Ab + (size_t)m_ * K_DIM + (KT) * BK + ((p_ ^ (m_ & 7)) << 4),\
                    (DST) + (it_ * 256 + w * 64) * 16);                          \
        }                                                                        \
    } while (0)

    // stage B tile (16KB = 1024x16B units): 4 iters
#define STAGE_B(KT)                                                              \
    do {                                                                         \
        _Pragma("unroll") for (int it_ = 0; it_ < 4; ++it_) {                    \
            const int idx_ = it_ * 256 + tid;                                    \
            const int n_ = idx_ >> 3, p_ = idx_ & 7;                             \
            async16(Bb + (size_t)n_ * K_DIM + (KT) * BK + ((p_ ^ (n_ & 7)) << 4),\
                    ldsB + (it_ * 256 + w * 64) * 16);                           \
        }                                                                        \
    } while (0)

#define READ_AK(BUF, KK)                                                         \
    do {                                                                         \
        _Pragma("unroll") for (int q_ = 0; q_ < 8; ++q_) {                       \
            const int r_ = wr * 128 + q_ * 16 + lr;                              \
            const int u_ = (KK) * 4 + lg;                                        \
            afk[KK][q_] = *reinterpret_cast<const i32x4*>(                       \
                (BUF) + r_ * BK + ((u_ ^ (r_ & 7)) << 4));                       \
        }                                                                        \
    } while (0)

#define READ_BK(KK)                                                              \
    do {                                                                         \
        _Pragma("unroll") for (int p_ = 0; p_ < 4; ++p_) {                       \
            const int r_ = wc * 64 + p_ * 16 + lr;                               \
            const int u_ = (KK) * 4 + lg;                                        \
            bfk[KK][p_] = *reinterpret_cast<const i32x4*>(                       \
                ldsB + r_ * BK + ((u_ ^ (r_ & 7)) << 4));                        \
        }                                                                        \
    } while (0)

#define CLUSTER(KK)                                                              \
    do {                                                                         \
        __builtin_amdgcn_s_setprio(1);                                           \
        _Pragma("unroll") for (int q_ = 0; q_ < 8; ++q_)                         \
        _Pragma("unroll") for (int p_ = 0; p_ < 4; ++p_)                         \
            acc[q_][p_] = __builtin_amdgcn_mfma_i32_16x16x64_i8(                 \
                afk[KK][q_], bfk[KK][p_], acc[q_][p_], 0, 0, 0);                 \
        __builtin_amdgcn_s_setprio(0);                                           \
    } while (0)

#define BAR __builtin_amdgcn_s_barrier()
#define SB0 __builtin_amdgcn_sched_barrier(0)
#define VMCNT8 asm volatile("s_waitcnt vmcnt(8)" ::: "memory")
#define LGKM(N) asm volatile("s_waitcnt lgkmcnt(" #N ")" ::: "memory")

    // one tile of the steady-state schedule
#define TILE_ONE(CURA, TB, TA2)                                                  \
    do {                                                                         \
        READ_AK(CURA, 0);                                                        \
        READ_BK(0);                                                              \
        SB0;                                                                     \
        READ_AK(CURA, 1);                                                        \
        READ_BK(1);                                                              \
        LGKM(12);                                                                \
        SB0;                                                                     \
        CLUSTER(0);                                                              \
        LGKM(0);                                                                 \
        SB0;                                                                     \
        BAR; /* mid: all waves done reading CURA & ldsB */                       \
        STAGE_B(TB);                                                             \
        STAGE_A(CURA, TA2);                                                      \
        SB0; /* stages issue before cluster1 */                                  \
        CLUSTER(1);                                                              \
        VMCNT8; /* drains A(t+1)+B(t+1); leaves A(t+2) in flight */              \
        BAR;    /* boundary */                                                   \
    } while (0)

    i32x4 afk[2][8], bfk[2][4];

    // ---- prologue: A(0)->A0 [8], B(0) [4], A(1)->A1 [8]; wait 12 oldest ----
    STAGE_A(ldsA0, 0);
    STAGE_B(0);
    STAGE_A(ldsA1, 1);
    VMCNT8;  // A(0)+B(0) landed; A(1)'s 8 in flight
    BAR;

#pragma unroll 1
    for (int it2 = 0; it2 < NT / 2; ++it2) {
        const int t = 2 * it2;
        const int tb1 = (t + 1 < NT) ? t + 1 : NT - 1;  // clamped tail stages
        const int ta2 = (t + 2 < NT) ? t + 2 : NT - 1;  // (dead-region writes,
        const int tb2 = ta2;                            //  counts preserved)
        const int ta3 = (t + 3 < NT) ? t + 3 : NT - 1;

        TILE_ONE(ldsA0, tb1, ta2);  // tile t:   stage B(t+1), A(t+2)->A0
        TILE_ONE(ldsA1, tb2, ta3);  // tile t+1: stage B(t+2), A(t+3)->A1
    }

    // ---- epilogue: C/D layout col = lane&15, row = (lane>>4)*4 + reg ----
    const float* asp = ascale + row0 + wr * 128;
    const float* wsp = wscale + col0 + wc * 64;
    float wsv[4];
#pragma unroll
    for (int nf = 0; nf < 4; ++nf) wsv[nf] = wsp[nf * 16 + lr];
    float* outBase = out + (row0 + wr * 128) * (size_t)N_DIM + col0 + wc * 64;
#pragma unroll
    for (int mf = 0; mf < 8; ++mf) {
#pragma unroll
        for (int j = 0; j < 4; ++j) {
            const int r = mf * 16 + lg * 4 + j;
            const float av = asp[r];
            float* orow = outBase + (size_t)r * N_DIM;
#pragma unroll
            for (int nf = 0; nf < 4; ++nf) {
                orow[nf * 16 + lr] = (float)acc[mf][nf][j] * av * wsv[nf];
            }
        }
    }
#undef STAGE_A
#undef STAGE_B
#undef READ_AK
#undef READ_BK
#undef CLUSTER
#undef TILE_ONE
#undef BAR
#undef SB0
#undef VMCNT8
#undef LGKM
}

extern "C" void kernel_launch(void* const* d_in, const int* in_sizes, int n_in,
                              void* d_out, int out_size, void* d_ws, size_t ws_size,
                              hipStream_t stream) {
    const float* x = (const float*)d_in[0];
    const int* w32 = (const int*)d_in[1];
    const float* wscale = (const float*)d_in[2];
    float* out = (float*)d_out;

    uint8_t* ws = (uint8_t*)d_ws;
    uint32_t* xq = (uint32_t*)ws;                                  // 64 MiB
    float* xscale = (float*)(ws + (size_t)M_DIM * K_DIM);          // 64 KiB
    uint8_t* wq = ws + (size_t)M_DIM * K_DIM + (size_t)M_DIM * 4;  // 16 MiB

    pack_w_kernel<<<dim3((N_DIM * K_DIM / 4 + 255) / 256), 256, 0, stream>>>(
        w32, (uint32_t*)wq, N_DIM * K_DIM / 4);
    quant_kernel<<<dim3(M_DIM), 256, 0, stream>>>(x, xq, xscale);
    gemm_kernel<<<dim3((M_DIM / BM) * (N_DIM / BN)), 256, 0, stream>>>(
        (const uint8_t*)xq, xscale, wq, wscale, out);
}